// Round 12
// baseline (416.654 us; speedup 1.0000x reference)
//
#include <hip/hip_runtime.h>
#include <stdint.h>
#include <stddef.h>

typedef int v4i  __attribute__((ext_vector_type(4)));
typedef int v16i __attribute__((ext_vector_type(16)));
typedef _Float16 vh8 __attribute__((ext_vector_type(8)));

#define GELU_A   (-0.2888f)
#define GELU_B   (-1.769f)
#define INV_SQRT2 0.70710678118654752440f

// async 16B global->LDS (lane i's 16B lands at ldsbase + i*16; ldsbase wave-uniform)
#define GLD16(gp, lp) __builtin_amdgcn_global_load_lds( \
    (const __attribute__((address_space(1))) unsigned int*)(gp), \
    (__attribute__((address_space(3))) unsigned int*)(lp), 16, 0, 0)

// gfx9 s_waitcnt imm: vmcnt[3:0]=bits3:0, expcnt=bits6:4, lgkmcnt=bits11:8
#define WAIT_VM4   0x0F74   // vmcnt(4)
#define WAIT_VM2   0x0F72   // vmcnt(2)
#define WAIT_VM0   0x0F70   // vmcnt(0)
#define WAIT_LGKM0 0xC07F   // lgkmcnt(0), vmcnt free (=63)

// scalar slots: sc[0]=enc(xmin) sc[1]=enc(gmin)  [init 0xFFFFFFFF]
//               sc[2]=enc(xmax) sc[3]=|w1|max bits sc[4]=|w2|max bits sc[5]=enc(gmax) [init 0]

__device__ __forceinline__ unsigned enc_f(float f){
  unsigned u = __float_as_uint(f);
  return (u & 0x80000000u) ? ~u : (u | 0x80000000u);
}
__device__ __forceinline__ float dec_f(unsigned e){
  unsigned u = (e & 0x80000000u) ? (e & 0x7FFFFFFFu) : ~u;
  return __uint_as_float(u);
}
// NOTE: dec_f must invert enc_f exactly. (e&0x8000...) set means original was
// non-negative (enc set the sign bit): decode by clearing it; else decode ~e.
__device__ __forceinline__ float dec_f_fix(unsigned e){
  unsigned u = (e & 0x80000000u) ? (e & 0x7FFFFFFFu) : ~e;
  return __uint_as_float(u);
}

__device__ __forceinline__ float int_gelu_f(float x){
  float t = x * INV_SQRT2;
  float at = fminf(fabsf(t), 1.769f);
  float u = at + GELU_B;                 // in [-1.769, 0]
  float p = GELU_A * (u * u) + 1.0f;
  float L = (t > 0.0f) ? p : ((t < 0.0f) ? -p : 0.0f);
  return x * 0.5f * (1.0f + L);
}

// quantize 8 fp16 (one v4i) -> 8 packed (q-128) int8 in uint2.
// EXACT same expression as the old quant_g: rintf(g/qs)+qzp, clamp, -128.
__device__ __forceinline__ uint2 quant8_g(v4i v, float qs, float qzp){
  vh8 h = *(vh8*)&v;
  unsigned lo = 0, hi = 0;
#pragma unroll
  for (int j = 0; j < 4; j++){
    int q = (int)fminf(fmaxf(rintf((float)h[j] / qs) + qzp, 0.0f), 255.0f) - 128;
    lo |= ((unsigned)(q & 255)) << (8 * j);
  }
#pragma unroll
  for (int j = 0; j < 4; j++){
    int q = (int)fminf(fmaxf(rintf((float)h[4 + j] / qs) + qzp, 0.0f), 255.0f) - 128;
    hi |= ((unsigned)(q & 255)) << (8 * j);
  }
  uint2 r; r.x = lo; r.y = hi; return r;
}

// blocks [0,1024): x min/max; [1024,1152): absmax w1 -> sc[3]; [1152,1280): absmax w2 -> sc[4]
__global__ __launch_bounds__(256) void reduce_stats(
    const float4* __restrict__ x, int nx4,
    const float4* __restrict__ w1, int n14,
    const float4* __restrict__ w2, int n24,
    unsigned* __restrict__ sc)
{
  __shared__ float ra[256], rb[256];
  const int tid = threadIdx.x;
  const int b = blockIdx.x;
  if (b < 1024){
    float lmin = 3.4e38f, lmax = -3.4e38f;
    for (long i = (long)b * 256 + tid; i < nx4; i += 1024L * 256L){
      float4 v = x[i];
      lmin = fminf(lmin, fminf(fminf(v.x, v.y), fminf(v.z, v.w)));
      lmax = fmaxf(lmax, fmaxf(fmaxf(v.x, v.y), fmaxf(v.z, v.w)));
    }
    ra[tid] = lmin; rb[tid] = lmax;
    __syncthreads();
    for (int s = 128; s > 0; s >>= 1){
      if (tid < s){ ra[tid] = fminf(ra[tid], ra[tid + s]); rb[tid] = fmaxf(rb[tid], rb[tid + s]); }
      __syncthreads();
    }
    if (tid == 0){
      atomicMin(&sc[0], enc_f(ra[0]));
      atomicMax(&sc[2], enc_f(rb[0]));
    }
  } else {
    const float4* w; int n4; int slot; int bl;
    if (b < 1152){ w = w1; n4 = n14; slot = 3; bl = b - 1024; }
    else         { w = w2; n4 = n24; slot = 4; bl = b - 1152; }
    float la = 0.0f;
    for (long i = (long)bl * 256 + tid; i < n4; i += 128L * 256L){
      float4 v = w[i];
      la = fmaxf(la, fmaxf(fmaxf(fabsf(v.x), fabsf(v.y)), fmaxf(fabsf(v.z), fabsf(v.w))));
    }
    ra[tid] = la;
    __syncthreads();
    for (int s = 128; s > 0; s >>= 1){
      if (tid < s) ra[tid] = fmaxf(ra[tid], ra[tid + s]);
      __syncthreads();
    }
    if (tid == 0) atomicMax(&sc[slot], __float_as_uint(ra[0]));
  }
}

// fused: blocks [0,2048) act-quant x -> qx ((q-128) int8, packed u32);
//        blocks [2048, 2048+H+D) weight-quant rows (+row sums)
__global__ __launch_bounds__(256) void quant_all(
    const float4* __restrict__ x, unsigned* __restrict__ qx, long nx4,
    const float* __restrict__ w1, const float* __restrict__ w2,
    int8_t* __restrict__ qw1, int8_t* __restrict__ qw2,
    int* __restrict__ rs1, int* __restrict__ rs2,
    const unsigned* __restrict__ sc, int H, int D)
{
  const int tid = threadIdx.x;
  const int b = blockIdx.x;
  if (b < 2048){
    const float vmin = dec_f_fix(sc[0]);
    const float vmax = dec_f_fix(sc[2]);
    const float s  = fmaxf(vmax - vmin, 1e-8f) / 255.0f;
    const float zp = rintf(-vmin / s);
    for (long i = (long)b * 256 + tid; i < nx4; i += 2048L * 256L){
      float4 v = x[i];
      int q0 = (int)fminf(fmaxf(rintf(v.x / s) + zp, 0.0f), 255.0f) - 128;
      int q1 = (int)fminf(fmaxf(rintf(v.y / s) + zp, 0.0f), 255.0f) - 128;
      int q2 = (int)fminf(fmaxf(rintf(v.z / s) + zp, 0.0f), 255.0f) - 128;
      int q3 = (int)fminf(fmaxf(rintf(v.w / s) + zp, 0.0f), 255.0f) - 128;
      qx[i] = ((unsigned)(q0 & 255)) | ((unsigned)(q1 & 255) << 8) |
              ((unsigned)(q2 & 255) << 16) | ((unsigned)(q3 & 255) << 24);
    }
  } else {
    __shared__ int red[256];
    const int wb = b - 2048;
    const float* w; int8_t* q; int* rs; int K; int n; float s;
    if (wb < H){ w = w1; q = qw1; rs = rs1; K = D; n = wb;
                 s = fmaxf(__uint_as_float(sc[3]), 1e-8f) / 127.0f; }
    else       { w = w2; q = qw2; rs = rs2; K = H; n = wb - H;
                 s = fmaxf(__uint_as_float(sc[4]), 1e-8f) / 127.0f; }
    int sum = 0;
    for (int k = tid; k < K; k += 256){
      float v = w[(size_t)n * K + k];
      float qf = fminf(fmaxf(rintf(v / s), -128.0f), 127.0f);
      int qi = (int)qf;
      q[(size_t)n * K + k] = (int8_t)qi;
      sum += qi;
    }
    red[tid] = sum;
    __syncthreads();
    for (int st = 128; st > 0; st >>= 1){
      if (tid < st) red[tid] += red[tid + st];
      __syncthreads();
    }
    if (tid == 0) rs[n] = red[0];
  }
}

// MODE 0: h->gelu-> g min/max atomics only (no store)          [fallback pass A]
// MODE 3: h->gelu-> store g fp16 (LDS-transposed, coalesced) + g min/max [main pass A]
// MODE 2: h->gelu-> quantize with g stats -> store int8 (q-128) [fallback pass B]
// MODE 1: h + bias -> store fp32 out                            [fallback GEMM2]
//
// R8 structure EXACTLY (best measured: total 307.1us, GEMM1 93us).
template<int MODE>
__global__ __launch_bounds__(256) void gemm_i8(
    const int8_t* __restrict__ A, const int8_t* __restrict__ Bm,
    const int* __restrict__ rowsum, const float* __restrict__ bias,
    void* __restrict__ Cout, int M, int N, int K,
    unsigned* __restrict__ sc)
{
  __shared__ __align__(16) int8_t lds[3][16384];   // per buf: A @0, B @8192

  const int tid  = threadIdx.x;
  const int lane = tid & 63;
  const int wave = tid >> 6;
  const int l31  = lane & 31;
  const int kh   = lane >> 5;          // 0/1 : which 16B half of a 32-k block
  const int n0   = blockIdx.x * 128;
  const int m0   = blockIdx.y * 128;
  const int wm   = (wave & 1) * 64;
  const int wn   = (wave >> 1) * 64;

  int aoffs[2], boffs[2];
  const int ldst[2] = { wave * 2048, wave * 2048 + 1024 };
#pragma unroll
  for (int t = 0; t < 2; t++){
    int rowl = wave * 32 + t * 16 + (lane >> 2);       // local tile row 0..127
    int csw  = ((lane & 3) ^ ((rowl >> 1) & 3)) << 4;  // swizzled source chunk
    int ga = m0 + rowl; if (ga >= M) ga = M - 1;
    aoffs[t] = ga * K + csw;
    boffs[t] = (n0 + rowl) * K + csw;
  }

  const int w2  = (l31 >> 1) & 3;
  const int sA0 = (kh ^ w2) << 4;
  int arow[2], brow[2];
#pragma unroll
  for (int mi = 0; mi < 2; mi++){
    arow[mi] = (wm + mi * 32 + l31) * 64;
    brow[mi] = (wn + mi * 32 + l31) * 64;
  }

  v16i acc[2][2] = {};
  const int NT = K >> 6;

#pragma unroll
  for (int t = 0; t < 2; t++){
    GLD16(A  + aoffs[t],      &lds[0][ldst[t]]);
    GLD16(Bm + boffs[t],      &lds[0][8192 + ldst[t]]);
  }
#pragma unroll
  for (int t = 0; t < 2; t++){
    GLD16(A  + aoffs[t] + 64, &lds[1][ldst[t]]);
    GLD16(Bm + boffs[t] + 64, &lds[1][8192 + ldst[t]]);
  }

  for (int kt = 0; kt < NT; kt++){
    const int8_t* buf = lds[kt % 3];
    if (kt + 1 < NT) __builtin_amdgcn_s_waitcnt(WAIT_VM4);
    else             __builtin_amdgcn_s_waitcnt(WAIT_VM0);
    __builtin_amdgcn_s_barrier();          // raw: no compiler vmcnt(0) fence
    __builtin_amdgcn_sched_barrier(0);     // nothing (esp. next DMA) crosses up

    v4i af[2][2], bf[2][2];                // [kk][mi]
#pragma unroll
    for (int kk = 0; kk < 2; kk++){
      const int sb = sA0 ^ (kk << 5);
#pragma unroll
      for (int mi = 0; mi < 2; mi++){
        af[kk][mi] = *(const v4i*)(buf + arow[mi] + sb);
        bf[kk][mi] = *(const v4i*)(buf + 8192 + brow[mi] + sb);
      }
    }

    if (kt + 2 < NT){                      // prefetch distance 2
      int8_t* nbuf = lds[(kt + 2) % 3];
      const int ko = (kt + 2) << 6;
#pragma unroll
      for (int t = 0; t < 2; t++){
        GLD16(A  + aoffs[t] + ko, nbuf + ldst[t]);
        GLD16(Bm + boffs[t] + ko, nbuf + 8192 + ldst[t]);
      }
    }

#pragma unroll
    for (int kk = 0; kk < 2; kk++)
#pragma unroll
      for (int mi = 0; mi < 2; mi++)
#pragma unroll
        for (int nj = 0; nj < 2; nj++)
          acc[mi][nj] = __builtin_amdgcn_mfma_i32_32x32x32_i8(af[kk][mi], bf[kk][nj], acc[mi][nj], 0, 0, 0);
  }

  float s_h, off_h;
  if constexpr (MODE == 1){
    float gmin = dec_f_fix(sc[1]), gmax = dec_f_fix(sc[5]);
    float sg = fmaxf(gmax - gmin, 1e-8f) / 255.0f;
    float zp = rintf(-gmin / sg);
    float sw = fmaxf(__uint_as_float(sc[4]), 1e-8f) / 127.0f;
    s_h = sg * sw; off_h = 128.0f - zp;
  } else {
    float xmin = dec_f_fix(sc[0]), xmax = dec_f_fix(sc[2]);
    float sx = fmaxf(xmax - xmin, 1e-8f) / 255.0f;
    float zp = rintf(-xmin / sx);
    float sw = fmaxf(__uint_as_float(sc[3]), 1e-8f) / 127.0f;
    s_h = sx * sw; off_h = 128.0f - zp;
  }
  float qs = 1.0f, qzp = 0.0f;
  if constexpr (MODE == 2){
    float gmin = dec_f_fix(sc[1]), gmax = dec_f_fix(sc[5]);
    qs = fmaxf(gmax - gmin, 1e-8f) / 255.0f;
    qzp = rintf(-gmin / qs);
  }

  _Float16* tb = nullptr;
  if constexpr (MODE == 3){
    __syncthreads();                   // K-loop LDS traffic fully complete
    tb = (_Float16*)(&lds[0][0]) + (size_t)wave * 4608;
  }

  // C/D 32x32 layout: col = lane&31, row = (reg&3) + 8*(reg>>2) + 4*(lane>>5)
  float lmin = 3.4e38f, lmax = -3.4e38f;
#pragma unroll
  for (int nj = 0; nj < 2; nj++){
    const int n = n0 + wn + nj * 32 + l31;
    const float rsv = off_h * (float)rowsum[n];
    const float bv = bias[n];
#pragma unroll
    for (int mi = 0; mi < 2; mi++){
      const int mbase = m0 + wm + mi * 32 + 4 * kh;
#pragma unroll
      for (int r = 0; r < 16; r++){
        const int m = mbase + (r & 3) + 8 * (r >> 2);
        float h = s_h * ((float)acc[mi][nj][r] + rsv) + bv;
        if constexpr (MODE == 3){
          float gv = int_gelu_f(h);
          if (m < M){ lmin = fminf(lmin, gv); lmax = fmaxf(lmax, gv); }
          const int lmr = mi * 32 + 4 * kh + (r & 3) + 8 * (r >> 2);
          const int lnr = nj * 32 + l31;
          tb[lmr * 72 + lnr] = (_Float16)gv;
        } else if (m < M){
          if constexpr (MODE == 0){
            float gv = int_gelu_f(h);
            lmin = fminf(lmin, gv); lmax = fmaxf(lmax, gv);
          } else if constexpr (MODE == 2){
            float gv = int_gelu_f(h);
            float qf = fminf(fmaxf(rintf(gv / qs) + qzp, 0.0f), 255.0f);
            ((int8_t*)Cout)[(size_t)m * N + n] = (int8_t)((int)qf - 128);
          } else {
            ((float*)Cout)[(size_t)m * N + n] = h;
          }
        }
      }
    }
  }

  if constexpr (MODE == 3){
    __syncthreads();                   // drains lgkm; tb regions are per-wave private
#pragma unroll
    for (int it = 0; it < 8; it++){
      const int lr = it * 8 + (lane >> 3);         // local row 0..63
      const int c8 = (lane & 7) * 8;               // fp16 col start (16B chunks)
      vh8 v = *(const vh8*)(tb + lr * 72 + c8);    // 16B aligned (144B row stride)
      const int gm = m0 + wm + lr;
      if (gm < M)
        *(vh8*)((_Float16*)Cout + (size_t)gm * N + (n0 + wn + c8)) = v;
    }
  }

  if constexpr (MODE == 0 || MODE == 3){
    __syncthreads();                   // all waves done with LDS -> reuse as scratch
    float* redA = (float*)&lds[0][0];
    float* redB = ((float*)&lds[0][0]) + 256;
    redA[tid] = lmin; redB[tid] = lmax;
    __syncthreads();
    for (int st = 128; st > 0; st >>= 1){
      if (tid < st){
        redA[tid] = fminf(redA[tid], redA[tid + st]);
        redB[tid] = fmaxf(redB[tid], redB[tid + st]);
      }
      __syncthreads();
    }
    if (tid == 0){
      atomicMin(&sc[1], enc_f(redA[0]));
      atomicMax(&sc[5], enc_f(redB[0]));
    }
  }
}

// Fused GEMM2: A = g16 (fp16), quantized to (q-128) int8 DURING reg-staging
// (kills the quant_g kernel: -116MB traffic, -1 dispatch). B = qw2 int8 via
// R8's GLD16 3-buffer path (unchanged). Read side / MFMA / epilogue = R8 MODE 1.
// Per-iter ledger (issue order: A(kt+2)x4 loads, then B-DMA(kt+2)x2):
//   top of iter kt outstanding = [B(kt)x2, A(kt+1)x4, B(kt+1)x2] -> vmcnt(2)
//   drains B(kt)+A(kt+1), leaves B(kt+1) in flight (never 0 in steady state).
//   Then: barrier -> quantize A(kt+1) regs -> ds_write buf[(kt+1)%3] (BEFORE own
//   ds_reads: in-order lgkm queue => write complete before this wave's MFMA
//   lgkm-wait => before next barrier => visible to all readers at iter kt+1).
//   -> 8 ds_reads buf[kt%3] -> issue A(kt+2)/B(kt+2) -> 16 MFMAs.
__global__ __launch_bounds__(256) void gemm2_fused(
    const _Float16* __restrict__ Ag, const int8_t* __restrict__ Bm,
    const int* __restrict__ rowsum, const float* __restrict__ bias,
    float* __restrict__ out, int M, int N, int K,
    const unsigned* __restrict__ sc)
{
  __shared__ __align__(16) int8_t lds[3][16384];   // per buf: A @0, B @8192

  const int tid  = threadIdx.x;
  const int lane = tid & 63;
  const int wave = tid >> 6;
  const int l31  = lane & 31;
  const int kh   = lane >> 5;
  const int n0   = blockIdx.x * 128;
  const int m0   = blockIdx.y * 128;
  const int wm   = (wave & 1) * 64;
  const int wn   = (wave >> 1) * 64;

  // g-quant scalars (sc final: GEMM1 completed before this kernel)
  const float gmin = dec_f_fix(sc[1]), gmax = dec_f_fix(sc[5]);
  const float qs  = fmaxf(gmax - gmin, 1e-8f) / 255.0f;
  const float qzp = rintf(-gmin / qs);

  long aoffs[2]; int boffs[2];
  const int ldst[2] = { wave * 2048, wave * 2048 + 1024 };
#pragma unroll
  for (int t = 0; t < 2; t++){
    int rowl = wave * 32 + t * 16 + (lane >> 2);
    int ch   = (lane & 3) ^ ((rowl >> 1) & 3);         // swizzled 16-k chunk
    int ga = m0 + rowl; if (ga >= M) ga = M - 1;
    aoffs[t] = (long)ga * K + (long)ch * 16;           // fp16 ELEMENT offset
    boffs[t] = (n0 + rowl) * K + (ch << 4);            // int8 byte offset
  }

  const int w2  = (l31 >> 1) & 3;
  const int sA0 = (kh ^ w2) << 4;
  int arow[2], brow[2];
#pragma unroll
  for (int mi = 0; mi < 2; mi++){
    arow[mi] = (wm + mi * 32 + l31) * 64;
    brow[mi] = (wn + mi * 32 + l31) * 64;
  }

  v16i acc[2][2] = {};
  const int NT = K >> 6;                 // 48

  v4i ap[2][2], an[2][2];                // A regs: prologue tile 0 / in-flight

  // prologue issue order: A0 x4, A1 x4, B0 x2, B1 x2
#pragma unroll
  for (int t = 0; t < 2; t++){
    const int8_t* p = (const int8_t*)(Ag + aoffs[t]);
    ap[t][0] = *(const v4i*)p; ap[t][1] = *(const v4i*)(p + 16);
  }
#pragma unroll
  for (int t = 0; t < 2; t++){
    const int8_t* p = (const int8_t*)(Ag + aoffs[t] + 64);
    an[t][0] = *(const v4i*)p; an[t][1] = *(const v4i*)(p + 16);
  }
  __builtin_amdgcn_sched_barrier(0);
#pragma unroll
  for (int t = 0; t < 2; t++) GLD16(Bm + boffs[t],      &lds[0][8192 + ldst[t]]);
#pragma unroll
  for (int t = 0; t < 2; t++) GLD16(Bm + boffs[t] + 64, &lds[1][8192 + ldst[t]]);
  __builtin_amdgcn_sched_barrier(0);

  // quantize tile0 A -> buf0 (compiler inserts counted vmcnt for ap reads,
  // leaving the B DMAs in flight); drain lgkm so writes are visible at barrier
#pragma unroll
  for (int t = 0; t < 2; t++){
    uint2 qa = quant8_g(ap[t][0], qs, qzp);
    uint2 qb = quant8_g(ap[t][1], qs, qzp);
    uint4 o; o.x = qa.x; o.y = qa.y; o.z = qb.x; o.w = qb.y;
    *(uint4*)(&lds[0][ldst[t] + lane * 16]) = o;
  }
  __builtin_amdgcn_s_waitcnt(WAIT_LGKM0);

  for (int kt = 0; kt < NT; kt++){
    const int8_t* buf = lds[kt % 3];
    if (kt + 1 < NT) __builtin_amdgcn_s_waitcnt(WAIT_VM2);
    else             __builtin_amdgcn_s_waitcnt(WAIT_VM0);
    __builtin_amdgcn_s_barrier();
    __builtin_amdgcn_sched_barrier(0);

    if (kt + 1 < NT){                    // stage A(kt+1): quantize regs -> LDS
      int8_t* wb = lds[(kt + 1) % 3];
#pragma unroll
      for (int t = 0; t < 2; t++){
        uint2 qa = quant8_g(an[t][0], qs, qzp);
        uint2 qb = quant8_g(an[t][1], qs, qzp);
        uint4 o; o.x = qa.x; o.y = qa.y; o.z = qb.x; o.w = qb.y;
        *(uint4*)(wb + ldst[t] + lane * 16) = o;
      }
    }
    __builtin_amdgcn_sched_barrier(0);

    v4i af[2][2], bf[2][2];
#pragma unroll
    for (int kk = 0; kk < 2; kk++){
      const int sb = sA0 ^ (kk << 5);
#pragma unroll
      for (int mi = 0; mi < 2; mi++){
        af[kk][mi] = *(const v4i*)(buf + arow[mi] + sb);
        bf[kk][mi] = *(const v4i*)(buf + 8192 + brow[mi] + sb);
      }
    }
    __builtin_amdgcn_sched_barrier(0);

    if (kt + 2 < NT){
      const int ko = (kt + 2) << 6;
#pragma unroll
      for (int t = 0; t < 2; t++){       // A loads first (WAR on an[] is safe:
        const int8_t* p = (const int8_t*)(Ag + aoffs[t] + ko);   // reads issued above)
        an[t][0] = *(const v4i*)p; an[t][1] = *(const v4i*)(p + 16);
      }
      __builtin_amdgcn_sched_barrier(0);
      int8_t* nb = lds[(kt + 2) % 3];
#pragma unroll
      for (int t = 0; t < 2; t++) GLD16(Bm + boffs[t] + ko, nb + 8192 + ldst[t]);
    }
    __builtin_amdgcn_sched_barrier(0);

#pragma unroll
    for (int kk = 0; kk < 2; kk++)
#pragma unroll
      for (int mi = 0; mi < 2; mi++)
#pragma unroll
        for (int nj = 0; nj < 2; nj++)
          acc[mi][nj] = __builtin_amdgcn_mfma_i32_32x32x32_i8(af[kk][mi], bf[kk][nj], acc[mi][nj], 0, 0, 0);
  }

  // epilogue (= R8 MODE 1)
  const float sw  = fmaxf(__uint_as_float(sc[4]), 1e-8f) / 127.0f;
  const float s_h = qs * sw;
  const float off_h = 128.0f - qzp;

#pragma unroll
  for (int nj = 0; nj < 2; nj++){
    const int n = n0 + wn + nj * 32 + l31;
    const float rsv = off_h * (float)rowsum[n];
    const float bv = bias[n];
#pragma unroll
    for (int mi = 0; mi < 2; mi++){
      const int mbase = m0 + wm + mi * 32 + 4 * kh;
#pragma unroll
      for (int r = 0; r < 16; r++){
        const int m = mbase + (r & 3) + 8 * (r >> 2);
        if (m < M){
          float h = s_h * ((float)acc[mi][nj][r] + rsv) + bv;
          out[(size_t)m * N + n] = h;
        }
      }
    }
  }
}

extern "C" void kernel_launch(void* const* d_in, const int* in_sizes, int n_in,
                              void* d_out, int out_size, void* d_ws, size_t ws_size,
                              hipStream_t stream)
{
  const float* x  = (const float*)d_in[0];
  const float* w1 = (const float*)d_in[1];
  const float* b1 = (const float*)d_in[2];
  const float* w2 = (const float*)d_in[3];
  const float* b2 = (const float*)d_in[4];
  float* out = (float*)d_out;

  const int H = in_sizes[2];            // 3072
  const int D = in_sizes[4];            // 768
  const int M = in_sizes[0] / D;        // 12608

  char* ws = (char*)d_ws;
  unsigned* sc = (unsigned*)ws;
  size_t off = 256;
  int8_t* qx  = (int8_t*)(ws + off); off += (size_t)M * D;   // 9.68 MB
  int8_t* qw1 = (int8_t*)(ws + off); off += (size_t)H * D;   // 2.36 MB
  int8_t* qw2 = (int8_t*)(ws + off); off += (size_t)D * H;   // 2.36 MB
  int* rs1 = (int*)(ws + off); off += (size_t)H * 4;
  int* rs2 = (int*)(ws + off); off += 4096;
  int8_t* qg  = (int8_t*)(ws + off); off += (size_t)M * H;   // 38.7 MB (fallback only)
  _Float16* g16 = (_Float16*)(ws + off);                      // 77.5 MB (big path)
  const size_t need_big = off + (size_t)M * H * 2;
  (void)n_in; (void)out_size;

  // scalar init: slots 0,1 = 0xFFFFFFFF (encoded +inf for min); 2..5 = 0
  hipMemsetAsync(sc, 0xFF, 8, stream);
  hipMemsetAsync(sc + 2, 0x00, 16, stream);

  reduce_stats<<<dim3(1280), dim3(256), 0, stream>>>(
      (const float4*)x, M * D / 4,
      (const float4*)w1, H * D / 4,
      (const float4*)w2, D * H / 4, sc);

  quant_all<<<dim3(2048 + H + D), dim3(256), 0, stream>>>(
      (const float4*)x, (unsigned*)qx, (long)M * D / 4,
      w1, w2, qw1, qw2, rs1, rs2, sc, H, D);

  const dim3 g1(H / 128, (M + 127) / 128), g2(D / 128, (M + 127) / 128), blk(256);

  if (ws_size >= need_big){
    // GEMM1 (single pass): g stats + store g fp16 (coalesced via LDS transpose)
    gemm_i8<3><<<g1, blk, 0, stream>>>(qx, qw1, rs1, b1, g16, M, H, D, sc);
    // GEMM2 with fused on-the-fly g quantization (quant_g eliminated)
    gemm2_fused<<<g2, blk, 0, stream>>>(g16, qw2, rs2, b2, out, M, D, H, sc);
  } else {
    // fallback: exact 2-pass GEMM1 (stats, then quantize), then int8 GEMM2
    gemm_i8<0><<<g1, blk, 0, stream>>>(qx, qw1, rs1, b1, nullptr, M, H, D, sc);
    gemm_i8<2><<<g1, blk, 0, stream>>>(qx, qw1, rs1, b1, qg, M, H, D, sc);
    gemm_i8<1><<<g2, blk, 0, stream>>>(qg, qw2, rs2, b2, out, M, D, H, sc);
  }
}

// Round 13
// 304.977 us; speedup vs baseline: 1.3662x; 1.3662x over previous
//
#include <hip/hip_runtime.h>
#include <stdint.h>
#include <stddef.h>

typedef int v4i  __attribute__((ext_vector_type(4)));
typedef int v16i __attribute__((ext_vector_type(16)));
typedef _Float16 vh8 __attribute__((ext_vector_type(8)));

#define GELU_A   (-0.2888f)
#define GELU_B   (-1.769f)
#define INV_SQRT2 0.70710678118654752440f

// async 16B global->LDS (lane i's 16B lands at ldsbase + i*16; ldsbase wave-uniform)
#define GLD16(gp, lp) __builtin_amdgcn_global_load_lds( \
    (const __attribute__((address_space(1))) unsigned int*)(gp), \
    (__attribute__((address_space(3))) unsigned int*)(lp), 16, 0, 0)

// gfx9 s_waitcnt immediates: vmcnt[3:0]=bits3:0, expcnt=bits6:4, lgkmcnt=bits11:8
#define WAIT_VM4 0x0F74   // vmcnt(4)
#define WAIT_VM0 0x0F70   // vmcnt(0)

// scalar slots: sc[0]=enc(xmin) sc[1]=enc(gmin)  [init 0xFFFFFFFF]
//               sc[2]=enc(xmax) sc[3]=|w1|max bits sc[4]=|w2|max bits sc[5]=enc(gmax) [init 0]

__device__ __forceinline__ unsigned enc_f(float f){
  unsigned u = __float_as_uint(f);
  return (u & 0x80000000u) ? ~u : (u | 0x80000000u);
}
__device__ __forceinline__ float dec_f(unsigned e){
  unsigned u = (e & 0x80000000u) ? (e & 0x7FFFFFFFu) : ~e;
  return __uint_as_float(u);
}

__device__ __forceinline__ float int_gelu_f(float x){
  float t = x * INV_SQRT2;
  float at = fminf(fabsf(t), 1.769f);
  float u = at + GELU_B;                 // in [-1.769, 0]
  float p = GELU_A * (u * u) + 1.0f;
  float L = (t > 0.0f) ? p : ((t < 0.0f) ? -p : 0.0f);
  return x * 0.5f * (1.0f + L);
}

// blocks [0,1024): x min/max; [1024,1152): absmax w1 -> sc[3]; [1152,1280): absmax w2 -> sc[4]
__global__ __launch_bounds__(256) void reduce_stats(
    const float4* __restrict__ x, int nx4,
    const float4* __restrict__ w1, int n14,
    const float4* __restrict__ w2, int n24,
    unsigned* __restrict__ sc)
{
  __shared__ float ra[256], rb[256];
  const int tid = threadIdx.x;
  const int b = blockIdx.x;
  if (b < 1024){
    float lmin = 3.4e38f, lmax = -3.4e38f;
    for (long i = (long)b * 256 + tid; i < nx4; i += 1024L * 256L){
      float4 v = x[i];
      lmin = fminf(lmin, fminf(fminf(v.x, v.y), fminf(v.z, v.w)));
      lmax = fmaxf(lmax, fmaxf(fmaxf(v.x, v.y), fmaxf(v.z, v.w)));
    }
    ra[tid] = lmin; rb[tid] = lmax;
    __syncthreads();
    for (int s = 128; s > 0; s >>= 1){
      if (tid < s){ ra[tid] = fminf(ra[tid], ra[tid + s]); rb[tid] = fmaxf(rb[tid], rb[tid + s]); }
      __syncthreads();
    }
    if (tid == 0){
      atomicMin(&sc[0], enc_f(ra[0]));
      atomicMax(&sc[2], enc_f(rb[0]));
    }
  } else {
    const float4* w; int n4; int slot; int bl;
    if (b < 1152){ w = w1; n4 = n14; slot = 3; bl = b - 1024; }
    else         { w = w2; n4 = n24; slot = 4; bl = b - 1152; }
    float la = 0.0f;
    for (long i = (long)bl * 256 + tid; i < n4; i += 128L * 256L){
      float4 v = w[i];
      la = fmaxf(la, fmaxf(fmaxf(fabsf(v.x), fabsf(v.y)), fmaxf(fabsf(v.z), fabsf(v.w))));
    }
    ra[tid] = la;
    __syncthreads();
    for (int s = 128; s > 0; s >>= 1){
      if (tid < s) ra[tid] = fmaxf(ra[tid], ra[tid + s]);
      __syncthreads();
    }
    if (tid == 0) atomicMax(&sc[slot], __float_as_uint(ra[0]));
  }
}

// fused: blocks [0,2048) act-quant x -> qx ((q-128) int8, packed u32);
//        blocks [2048, 2048+H+D) weight-quant rows (+row sums)
__global__ __launch_bounds__(256) void quant_all(
    const float4* __restrict__ x, unsigned* __restrict__ qx, long nx4,
    const float* __restrict__ w1, const float* __restrict__ w2,
    int8_t* __restrict__ qw1, int8_t* __restrict__ qw2,
    int* __restrict__ rs1, int* __restrict__ rs2,
    const unsigned* __restrict__ sc, int H, int D)
{
  const int tid = threadIdx.x;
  const int b = blockIdx.x;
  if (b < 2048){
    const float vmin = dec_f(sc[0]);
    const float vmax = dec_f(sc[2]);
    const float s  = fmaxf(vmax - vmin, 1e-8f) / 255.0f;
    const float zp = rintf(-vmin / s);
    for (long i = (long)b * 256 + tid; i < nx4; i += 2048L * 256L){
      float4 v = x[i];
      int q0 = (int)fminf(fmaxf(rintf(v.x / s) + zp, 0.0f), 255.0f) - 128;
      int q1 = (int)fminf(fmaxf(rintf(v.y / s) + zp, 0.0f), 255.0f) - 128;
      int q2 = (int)fminf(fmaxf(rintf(v.z / s) + zp, 0.0f), 255.0f) - 128;
      int q3 = (int)fminf(fmaxf(rintf(v.w / s) + zp, 0.0f), 255.0f) - 128;
      qx[i] = ((unsigned)(q0 & 255)) | ((unsigned)(q1 & 255) << 8) |
              ((unsigned)(q2 & 255) << 16) | ((unsigned)(q3 & 255) << 24);
    }
  } else {
    __shared__ int red[256];
    const int wb = b - 2048;
    const float* w; int8_t* q; int* rs; int K; int n; float s;
    if (wb < H){ w = w1; q = qw1; rs = rs1; K = D; n = wb;
                 s = fmaxf(__uint_as_float(sc[3]), 1e-8f) / 127.0f; }
    else       { w = w2; q = qw2; rs = rs2; K = H; n = wb - H;
                 s = fmaxf(__uint_as_float(sc[4]), 1e-8f) / 127.0f; }
    int sum = 0;
    for (int k = tid; k < K; k += 256){
      float v = w[(size_t)n * K + k];
      float qf = fminf(fmaxf(rintf(v / s), -128.0f), 127.0f);
      int qi = (int)qf;
      q[(size_t)n * K + k] = (int8_t)qi;
      sum += qi;
    }
    red[tid] = sum;
    __syncthreads();
    for (int st = 128; st > 0; st >>= 1){
      if (tid < st) red[tid] += red[tid + st];
      __syncthreads();
    }
    if (tid == 0) rs[n] = red[0];
  }
}

// elementwise: fp16 g -> int8 qg ((q-128)), using g stats
__global__ __launch_bounds__(256) void quant_g(
    const vh8* __restrict__ g, uint2* __restrict__ qg, long n8,
    const unsigned* __restrict__ sc)
{
  const float gmin = dec_f(sc[1]), gmax = dec_f(sc[5]);
  const float qs  = fmaxf(gmax - gmin, 1e-8f) / 255.0f;
  const float qzp = rintf(-gmin / qs);
  const long stride = (long)gridDim.x * blockDim.x;
  for (long i = (long)blockIdx.x * blockDim.x + threadIdx.x; i < n8; i += stride){
    vh8 v = g[i];
    unsigned lo = 0, hi = 0;
#pragma unroll
    for (int j = 0; j < 4; j++){
      int q = (int)fminf(fmaxf(rintf((float)v[j] / qs) + qzp, 0.0f), 255.0f) - 128;
      lo |= ((unsigned)(q & 255)) << (8 * j);
    }
#pragma unroll
    for (int j = 0; j < 4; j++){
      int q = (int)fminf(fmaxf(rintf((float)v[4 + j] / qs) + qzp, 0.0f), 255.0f) - 128;
      hi |= ((unsigned)(q & 255)) << (8 * j);
    }
    uint2 o; o.x = lo; o.y = hi;
    qg[i] = o;
  }
}

// MODE 0: h->gelu-> g min/max atomics only (no store)          [fallback pass A]
// MODE 3: h->gelu-> store g fp16 (LDS-transposed, coalesced) + g min/max [main pass A]
// MODE 2: h->gelu-> quantize with g stats -> store int8 (q-128) [fallback pass B]
// MODE 1: h + bias -> store fp32 out                            [GEMM2]
//
// R8 structure (session best: total 307.1us, GEMM1 93us): 128x128 tile, BK=64,
// mfma_i32_32x32x32_i8, 4 waves each 64x64 (2x2 of 32x32), 3-stage pipeline,
// 3 LDS buffers (48KB -> 3 blocks/CU), vmcnt(4) steady state, staging issued
// early (between frag reads and MFMAs), single barrier per iter.
// MODE 3 epilogue: wave-private padded LDS transpose (64x72 fp16, 144B row
// stride) then 8x {ds_read_b128 + global_store_dwordx4} coalesced full-line
// stores (R8 win: WRITE 105.8->75.8MB, GEMM1 102->93us).
// Session-falsified deltas (do not reintroduce): bigger tiles / 8-phase /
// flatmm / hybrid-B / 2-buffer (R1-R9), XCD swizzle + NT store (R10, null),
// quant_g widening (R11, null), fused GEMM2 quant (R12, VALU-bound, -2.2x).
template<int MODE>
__global__ __launch_bounds__(256) void gemm_i8(
    const int8_t* __restrict__ A, const int8_t* __restrict__ Bm,
    const int* __restrict__ rowsum, const float* __restrict__ bias,
    void* __restrict__ Cout, int M, int N, int K,
    unsigned* __restrict__ sc)
{
  __shared__ __align__(16) int8_t lds[3][16384];   // per buf: A @0, B @8192

  const int tid  = threadIdx.x;
  const int lane = tid & 63;
  const int wave = tid >> 6;
  const int l31  = lane & 31;
  const int kh   = lane >> 5;          // 0/1 : which 16B half of a 32-k block
  const int n0   = blockIdx.x * 128;
  const int m0   = blockIdx.y * 128;
  const int wm   = (wave & 1) * 64;
  const int wn   = (wave >> 1) * 64;

  // staging: wave w stages tile rows [32w,32w+32), 2 instrs of 16 rows each per
  // operand. lane L -> row rbase+(L>>2), LDS slot L&3, src chunk (L&3)^((row>>1)&3).
  int aoffs[2], boffs[2];
  const int ldst[2] = { wave * 2048, wave * 2048 + 1024 };
#pragma unroll
  for (int t = 0; t < 2; t++){
    int rowl = wave * 32 + t * 16 + (lane >> 2);       // local tile row 0..127
    int csw  = ((lane & 3) ^ ((rowl >> 1) & 3)) << 4;  // swizzled source chunk
    int ga = m0 + rowl; if (ga >= M) ga = M - 1;
    aoffs[t] = ga * K + csw;
    boffs[t] = (n0 + rowl) * K + csw;
  }

  // fragment read constants: slot s = (kk*2+kh) ^ ((l31>>1)&3)
  const int w2  = (l31 >> 1) & 3;
  const int sA0 = (kh ^ w2) << 4;
  int arow[2], brow[2];
#pragma unroll
  for (int mi = 0; mi < 2; mi++){
    arow[mi] = (wm + mi * 32 + l31) * 64;
    brow[mi] = (wn + mi * 32 + l31) * 64;
  }

  v16i acc[2][2] = {};
  const int NT = K >> 6;

  // prologue: stage tiles 0,1 into bufs 0,1 (issue order = vmcnt order)
#pragma unroll
  for (int t = 0; t < 2; t++){
    GLD16(A  + aoffs[t],      &lds[0][ldst[t]]);
    GLD16(Bm + boffs[t],      &lds[0][8192 + ldst[t]]);
  }
#pragma unroll
  for (int t = 0; t < 2; t++){
    GLD16(A  + aoffs[t] + 64, &lds[1][ldst[t]]);
    GLD16(Bm + boffs[t] + 64, &lds[1][8192 + ldst[t]]);
  }

  for (int kt = 0; kt < NT; kt++){
    const int8_t* buf = lds[kt % 3];
    if (kt + 1 < NT) __builtin_amdgcn_s_waitcnt(WAIT_VM4);
    else             __builtin_amdgcn_s_waitcnt(WAIT_VM0);
    __builtin_amdgcn_s_barrier();          // raw: no compiler vmcnt(0) fence
    __builtin_amdgcn_sched_barrier(0);     // nothing (esp. next DMA) crosses up

    v4i af[2][2], bf[2][2];                // [kk][mi]
#pragma unroll
    for (int kk = 0; kk < 2; kk++){
      const int sb = sA0 ^ (kk << 5);
#pragma unroll
      for (int mi = 0; mi < 2; mi++){
        af[kk][mi] = *(const v4i*)(buf + arow[mi] + sb);
        bf[kk][mi] = *(const v4i*)(buf + 8192 + brow[mi] + sb);
      }
    }

    if (kt + 2 < NT){                      // prefetch distance 2
      int8_t* nbuf = lds[(kt + 2) % 3];
      const int ko = (kt + 2) << 6;
#pragma unroll
      for (int t = 0; t < 2; t++){
        GLD16(A  + aoffs[t] + ko, nbuf + ldst[t]);
        GLD16(Bm + boffs[t] + ko, nbuf + 8192 + ldst[t]);
      }
    }

#pragma unroll
    for (int kk = 0; kk < 2; kk++)
#pragma unroll
      for (int mi = 0; mi < 2; mi++)
#pragma unroll
        for (int nj = 0; nj < 2; nj++)
          acc[mi][nj] = __builtin_amdgcn_mfma_i32_32x32x32_i8(af[kk][mi], bf[kk][nj], acc[mi][nj], 0, 0, 0);
  }

  // epilogue scalars
  float s_h, off_h;
  if constexpr (MODE == 1){
    float gmin = dec_f(sc[1]), gmax = dec_f(sc[5]);
    float sg = fmaxf(gmax - gmin, 1e-8f) / 255.0f;
    float zp = rintf(-gmin / sg);
    float sw = fmaxf(__uint_as_float(sc[4]), 1e-8f) / 127.0f;
    s_h = sg * sw; off_h = 128.0f - zp;
  } else {
    float xmin = dec_f(sc[0]), xmax = dec_f(sc[2]);
    float sx = fmaxf(xmax - xmin, 1e-8f) / 255.0f;
    float zp = rintf(-xmin / sx);
    float sw = fmaxf(__uint_as_float(sc[3]), 1e-8f) / 127.0f;
    s_h = sx * sw; off_h = 128.0f - zp;
  }
  float qs = 1.0f, qzp = 0.0f;
  if constexpr (MODE == 2){
    float gmin = dec_f(sc[1]), gmax = dec_f(sc[5]);
    qs = fmaxf(gmax - gmin, 1e-8f) / 255.0f;
    qzp = rintf(-gmin / qs);
  }

  // MODE 3: per-wave private LDS transpose buffer (64 rows x 72 fp16 = 9216B)
  _Float16* tb = nullptr;
  if constexpr (MODE == 3){
    __syncthreads();                   // K-loop LDS traffic fully complete
    tb = (_Float16*)(&lds[0][0]) + (size_t)wave * 4608;
  }

  // C/D 32x32 layout: col = lane&31, row = (reg&3) + 8*(reg>>2) + 4*(lane>>5)
  float lmin = 3.4e38f, lmax = -3.4e38f;
#pragma unroll
  for (int nj = 0; nj < 2; nj++){
    const int n = n0 + wn + nj * 32 + l31;
    const float rsv = off_h * (float)rowsum[n];
    const float bv = bias[n];
#pragma unroll
    for (int mi = 0; mi < 2; mi++){
      const int mbase = m0 + wm + mi * 32 + 4 * kh;
#pragma unroll
      for (int r = 0; r < 16; r++){
        const int m = mbase + (r & 3) + 8 * (r >> 2);
        float h = s_h * ((float)acc[mi][nj][r] + rsv) + bv;
        if constexpr (MODE == 3){
          float gv = int_gelu_f(h);
          if (m < M){ lmin = fminf(lmin, gv); lmax = fmaxf(lmax, gv); }
          const int lmr = mi * 32 + 4 * kh + (r & 3) + 8 * (r >> 2);
          const int lnr = nj * 32 + l31;
          tb[lmr * 72 + lnr] = (_Float16)gv;
        } else if (m < M){
          if constexpr (MODE == 0){
            float gv = int_gelu_f(h);
            lmin = fminf(lmin, gv); lmax = fmaxf(lmax, gv);
          } else if constexpr (MODE == 2){
            float gv = int_gelu_f(h);
            float qf = fminf(fmaxf(rintf(gv / qs) + qzp, 0.0f), 255.0f);
            ((int8_t*)Cout)[(size_t)m * N + n] = (int8_t)((int)qf - 128);
          } else {
            ((float*)Cout)[(size_t)m * N + n] = h;
          }
        }
      }
    }
  }

  if constexpr (MODE == 3){
    __syncthreads();                   // drains lgkm; tb regions are per-wave private
#pragma unroll
    for (int it = 0; it < 8; it++){
      const int lr = it * 8 + (lane >> 3);         // local row 0..63
      const int c8 = (lane & 7) * 8;               // fp16 col start (16B chunks)
      vh8 v = *(const vh8*)(tb + lr * 72 + c8);    // 16B aligned (144B row stride)
      const int gm = m0 + wm + lr;
      if (gm < M)
        *(vh8*)((_Float16*)Cout + (size_t)gm * N + (n0 + wn + c8)) = v;
    }
  }

  if constexpr (MODE == 0 || MODE == 3){
    __syncthreads();                   // all waves done with LDS -> reuse as scratch
    float* redA = (float*)&lds[0][0];
    float* redB = ((float*)&lds[0][0]) + 256;
    redA[tid] = lmin; redB[tid] = lmax;
    __syncthreads();
    for (int st = 128; st > 0; st >>= 1){
      if (tid < st){
        redA[tid] = fminf(redA[tid], redA[tid + st]);
        redB[tid] = fmaxf(redB[tid], redB[tid + st]);
      }
      __syncthreads();
    }
    if (tid == 0){
      atomicMin(&sc[1], enc_f(redA[0]));
      atomicMax(&sc[5], enc_f(redB[0]));
    }
  }
}

extern "C" void kernel_launch(void* const* d_in, const int* in_sizes, int n_in,
                              void* d_out, int out_size, void* d_ws, size_t ws_size,
                              hipStream_t stream)
{
  const float* x  = (const float*)d_in[0];
  const float* w1 = (const float*)d_in[1];
  const float* b1 = (const float*)d_in[2];
  const float* w2 = (const float*)d_in[3];
  const float* b2 = (const float*)d_in[4];
  float* out = (float*)d_out;

  const int H = in_sizes[2];            // 3072
  const int D = in_sizes[4];            // 768
  const int M = in_sizes[0] / D;        // 12608

  char* ws = (char*)d_ws;
  unsigned* sc = (unsigned*)ws;
  size_t off = 256;
  int8_t* qx  = (int8_t*)(ws + off); off += (size_t)M * D;   // 9.68 MB
  int8_t* qw1 = (int8_t*)(ws + off); off += (size_t)H * D;   // 2.36 MB
  int8_t* qw2 = (int8_t*)(ws + off); off += (size_t)D * H;   // 2.36 MB
  int* rs1 = (int*)(ws + off); off += (size_t)H * 4;
  int* rs2 = (int*)(ws + off); off += 4096;
  int8_t* qg  = (int8_t*)(ws + off); off += (size_t)M * H;   // 38.7 MB
  _Float16* g16 = (_Float16*)(ws + off);                      // 77.5 MB (big path)
  const size_t need_big = off + (size_t)M * H * 2;
  (void)n_in; (void)out_size;

  // scalar init: slots 0,1 = 0xFFFFFFFF (encoded +inf for min); 2..5 = 0
  hipMemsetAsync(sc, 0xFF, 8, stream);
  hipMemsetAsync(sc + 2, 0x00, 16, stream);

  reduce_stats<<<dim3(1280), dim3(256), 0, stream>>>(
      (const float4*)x, M * D / 4,
      (const float4*)w1, H * D / 4,
      (const float4*)w2, D * H / 4, sc);

  quant_all<<<dim3(2048 + H + D), dim3(256), 0, stream>>>(
      (const float4*)x, (unsigned*)qx, (long)M * D / 4,
      w1, w2, qw1, qw2, rs1, rs2, sc, H, D);

  const dim3 g1(H / 128, (M + 127) / 128), g2(D / 128, (M + 127) / 128), blk(256);

  if (ws_size >= need_big){
    // GEMM1 (single pass): g stats + store g fp16 (coalesced via LDS transpose)
    gemm_i8<3><<<g1, blk, 0, stream>>>(qx, qw1, rs1, b1, g16, M, H, D, sc);
    // elementwise quantize g -> qg
    quant_g<<<dim3(2048), blk, 0, stream>>>(
        (const vh8*)g16, (uint2*)qg, (long)M * H / 8, sc);
  } else {
    // fallback: exact 2-pass GEMM1 (stats, then quantize)
    gemm_i8<0><<<g1, blk, 0, stream>>>(qx, qw1, rs1, b1, nullptr, M, H, D, sc);
    gemm_i8<2><<<g1, blk, 0, stream>>>(qx, qw1, rs1, b1, qg, M, H, D, sc);
  }

  // GEMM2: out = qg @ qw2^T + b2
  gemm_i8<1><<<g2, blk, 0, stream>>>(qg, qw2, rs2, b2, out, M, D, H, sc);
}